// Round 5
// baseline (49938.574 us; speedup 1.0000x reference)
//
#include <hip/hip_runtime.h>
#include <cmath>

#define NB   256
#define NT   64
#define DATA 256
#define DD   264
#define DDP  272     // W0 rows padded to 272 floats (1088B, 64B-aligned)
#define WID  256
#define NSUB 4
#define NTH  512

// d_ws float offsets
#define WS_W0P 0                      // [256][272] padded row-major W0
#define WS_W1T (WS_W0P + 256 * DDP)   // [256][256] k-major W1 (W1T[k][j] = W1[j][k])
#define WS_W2T (WS_W1T + 256 * 256)   // [256][256] k-major W2

// LDS layout (float offsets)
#define NK_LDS 136
#define L_W1LO 0                         // [136][256] = 34816
#define L_PS   (L_W1LO + NK_LDS * 256)   // [8][256]   = 2048
#define L_Y    (L_PS + 8 * 256)          // 272 (pads zero)
#define L_IN   (L_Y + DDP)               // 272 (pads zero)
#define L_K    (L_IN + DDP)              // 272
#define L_ACC  (L_K + DDP)               // 272
#define L_HA   (L_ACC + DDP)             // 272
#define L_HB   (L_HA + DDP)              // 272
#define L_B0   (L_HB + DDP)              // 256
#define L_B1   (L_B0 + 256)              // 256
#define L_B2   (L_B1 + 256)              // 256
#define L_B3   (L_B2 + 256)              // 264 (reserve 272)
#define LDS_FLOATS (L_B3 + DDP)          // 39536 floats = 158,144 B -> 1 block/CU

__global__ void prep(const float* __restrict__ W0, const float* __restrict__ W1,
                     const float* __restrict__ W2, float* __restrict__ ws) {
  int tid = blockIdx.x * blockDim.x + threadIdx.x;
  int stride = gridDim.x * blockDim.x;
  for (int i = tid; i < 256 * DDP; i += stride) {
    int j = i / DDP, m = i - j * DDP;
    ws[WS_W0P + i] = (m < DD) ? W0[j * DD + m] : 0.f;
  }
  for (int i = tid; i < 256 * 256; i += stride) {
    int k = i >> 8, j = i & 255;
    ws[WS_W1T + i] = W1[j * 256 + k];
    ws[WS_W2T + i] = W2[j * 256 + k];
  }
}

__global__ __launch_bounds__(NTH, 2) void node_integrate(
    const float* __restrict__ ts, const float* __restrict__ xs,
    const float* __restrict__ a_sample,
    const float* __restrict__ b0g, const float* __restrict__ b1g,
    const float* __restrict__ b2g, const float* __restrict__ b3g,
    const float* __restrict__ W3, const float* __restrict__ ws,
    float* __restrict__ out) {
  extern __shared__ float sm[];
  const int b   = blockIdx.x;
  const int tid = threadIdx.x;
  const int w   = tid >> 6;   // wave 0..7
  const int l   = tid & 63;   // lane
  const int rr  = l >> 2;     // row-slot 0..15
  const int c   = l & 3;      // quarter-row 0..3

  // ---- one-time fills ----
  for (int i = tid; i < WID; i += NTH) {
    sm[L_B0 + i] = b0g[i];
    sm[L_B1 + i] = b1g[i];
    sm[L_B2 + i] = b2g[i];
  }
  for (int i = tid; i < DD; i += NTH) sm[L_B3 + i] = b3g[i];
  {
    const float4* src = (const float4*)(ws + WS_W1T);
    float4* dst = (float4*)(sm + L_W1LO);
    for (int i = tid; i < NK_LDS * 64; i += NTH) dst[i] = src[i];
  }
  // Register-resident weights: literal-indexed only, never passed anywhere.
  float4 w1r[15];   // W1 k = 136 + w + 8i
  float4 w2r[32];   // W2 k = w + 8i
  {
    const float4* w1t = (const float4*)(ws + WS_W1T);
    const float4* w2t = (const float4*)(ws + WS_W2T);
#pragma unroll
    for (int i = 0; i < 15; ++i) w1r[i] = w1t[(NK_LDS + w + 8 * i) * 64 + l];
#pragma unroll
    for (int i = 0; i < 32; ++i) w2r[i] = w2t[(w + 8 * i) * 64 + l];
  }
  // y0 = concat(a * exp(-0.1*t0) * sin(pi*x), zeros(AUG)); pads [264,272) = 0
  if (tid < DDP) {
    float v = 0.f;
    if (tid < DATA) {
      float x = xs[(size_t)b * DATA + tid];
      float scale = a_sample[b] * expf(-0.1f * ts[0]);
      v = scale * sinf(3.14159265358979323846f * x);
    }
    sm[L_Y + tid]  = v;
    sm[L_IN + tid] = 0.f;
  }
  __syncthreads();

  if (tid < DATA) out[((size_t)b * NT) * DATA + tid] = sm[L_Y + tid];

  const float* W0p = ws + WS_W0P;

#pragma unroll 1
  for (int t = 0; t < NT - 1; ++t) {
    const float dt = ts[t + 1] - ts[t];
    const float h  = dt * (1.0f / NSUB);
#pragma unroll 1
    for (int sub = 0; sub < NSUB; ++sub) {
#pragma unroll 1
      for (int s = 0; s < 3; ++s) {
        const float4* fin4 = (const float4*)(sm + ((s == 0) ? L_Y : L_IN));

        // ---- L0: hA = tanh(W0 @ fin + b0); streamed, 16 rows x 64B per instr
#pragma unroll
        for (int ch = 0; ch < 2; ++ch) {
          const int j = w + 8 * (16 * ch + rr);
          const float4* wr = (const float4*)(W0p + j * DDP);
          float acc = 0.f;
#pragma unroll
          for (int it = 0; it < 17; ++it) {
            float4 wv = wr[4 * it + c];
            float4 fv = fin4[4 * it + c];
            acc = fmaf(wv.x, fv.x, acc);
            acc = fmaf(wv.y, fv.y, acc);
            acc = fmaf(wv.z, fv.z, acc);
            acc = fmaf(wv.w, fv.w, acc);
          }
          acc += __shfl_xor(acc, 1);
          acc += __shfl_xor(acc, 2);
          if (c == 0) sm[L_HA + j] = tanhf(acc + sm[L_B0 + j]);
        }
        __syncthreads();

        // ---- L1: hB = tanh(W1 @ hA + b1); LDS k<136, regs k>=136
        {
          float4 acc;
          acc.x = acc.y = acc.z = acc.w = 0.f;
#pragma unroll
          for (int i = 0; i < 17; ++i) {
            const int k = w + 8 * i;                       // < 136
            const float fk = sm[L_HA + k];
            const float4 wv = ((const float4*)(sm + L_W1LO))[k * 64 + l];
            acc.x = fmaf(wv.x, fk, acc.x);
            acc.y = fmaf(wv.y, fk, acc.y);
            acc.z = fmaf(wv.z, fk, acc.z);
            acc.w = fmaf(wv.w, fk, acc.w);
          }
#pragma unroll
          for (int i = 0; i < 15; ++i) {
            const float fk = sm[L_HA + NK_LDS + w + 8 * i];
            acc.x = fmaf(w1r[i].x, fk, acc.x);
            acc.y = fmaf(w1r[i].y, fk, acc.y);
            acc.z = fmaf(w1r[i].z, fk, acc.z);
            acc.w = fmaf(w1r[i].w, fk, acc.w);
          }
          ((float4*)(sm + L_PS + w * WID))[l] = acc;
        }
        __syncthreads();
        if (tid < WID) {
          float sacc = sm[L_B1 + tid];
#pragma unroll
          for (int ww = 0; ww < 8; ++ww) sacc += sm[L_PS + ww * WID + tid];
          sm[L_HB + tid] = tanhf(sacc);
        }
        __syncthreads();

        // ---- L2: hA = tanh(W2 @ hB + b2); all-register
        {
          float4 acc;
          acc.x = acc.y = acc.z = acc.w = 0.f;
#pragma unroll
          for (int i = 0; i < 32; ++i) {
            const float fk = sm[L_HB + w + 8 * i];
            acc.x = fmaf(w2r[i].x, fk, acc.x);
            acc.y = fmaf(w2r[i].y, fk, acc.y);
            acc.z = fmaf(w2r[i].z, fk, acc.z);
            acc.w = fmaf(w2r[i].w, fk, acc.w);
          }
          ((float4*)(sm + L_PS + w * WID))[l] = acc;
        }
        __syncthreads();
        if (tid < WID) {
          float sacc = sm[L_B2 + tid];
#pragma unroll
          for (int ww = 0; ww < 8; ++ww) sacc += sm[L_PS + ww * WID + tid];
          sm[L_HA + tid] = tanhf(sacc);
        }
        __syncthreads();

        // ---- L3: k = W3 @ hA + b3; streamed, rows 1KB-aligned
        {
          const float4* h4 = (const float4*)(sm + L_HA);
#pragma unroll
          for (int ch = 0; ch < 2; ++ch) {
            const int j = w + 8 * (16 * ch + rr);
            const float4* wr = (const float4*)(W3 + (size_t)j * WID);
            float acc = 0.f;
#pragma unroll
            for (int it = 0; it < 16; ++it) {
              float4 wv = wr[4 * it + c];
              float4 fv = h4[4 * it + c];
              acc = fmaf(wv.x, fv.x, acc);
              acc = fmaf(wv.y, fv.y, acc);
              acc = fmaf(wv.z, fv.z, acc);
              acc = fmaf(wv.w, fv.w, acc);
            }
            acc += __shfl_xor(acc, 1);
            acc += __shfl_xor(acc, 2);
            if (c == 0) sm[L_K + j] = acc + sm[L_B3 + j];
          }
          if (rr == 0) {  // rows 256..263: one per wave
            const int j = 256 + w;
            const float4* wr = (const float4*)(W3 + (size_t)j * WID);
            float acc = 0.f;
#pragma unroll
            for (int it = 0; it < 16; ++it) {
              float4 wv = wr[4 * it + c];
              float4 fv = h4[4 * it + c];
              acc = fmaf(wv.x, fv.x, acc);
              acc = fmaf(wv.y, fv.y, acc);
              acc = fmaf(wv.z, fv.z, acc);
              acc = fmaf(wv.w, fv.w, acc);
            }
            acc += __shfl_xor(acc, 1);
            acc += __shfl_xor(acc, 2);
            if (c == 0) sm[L_K + j] = acc + sm[L_B3 + j];
          }
        }
        __syncthreads();

        // ---- RK combine ----
        if (tid < DD) {
          const float kv = sm[L_K + tid];
          if (s == 0) {
            sm[L_ACC + tid] = (2.0f / 9.0f) * kv;
            sm[L_IN + tid]  = sm[L_Y + tid] + 0.5f * h * kv;
          } else if (s == 1) {
            sm[L_ACC + tid] += (1.0f / 3.0f) * kv;
            sm[L_IN + tid]   = sm[L_Y + tid] + 0.75f * h * kv;
          } else {
            sm[L_Y + tid] += h * (sm[L_ACC + tid] + (4.0f / 9.0f) * kv);
          }
        }
        __syncthreads();
      }
    }
    if (tid < DATA) out[((size_t)b * NT + (t + 1)) * DATA + tid] = sm[L_Y + tid];
  }
}

extern "C" void kernel_launch(void* const* d_in, const int* in_sizes, int n_in,
                              void* d_out, int out_size, void* d_ws, size_t ws_size,
                              hipStream_t stream) {
  const float* ts = (const float*)d_in[0];
  const float* xs = (const float*)d_in[1];
  const float* a  = (const float*)d_in[2];
  const float* W0 = (const float*)d_in[3];
  const float* b0 = (const float*)d_in[4];
  const float* W1 = (const float*)d_in[5];
  const float* b1 = (const float*)d_in[6];
  const float* W2 = (const float*)d_in[7];
  const float* b2 = (const float*)d_in[8];
  const float* W3 = (const float*)d_in[9];
  const float* b3 = (const float*)d_in[10];
  float* ws  = (float*)d_ws;
  float* out = (float*)d_out;

  const size_t lds_bytes = LDS_FLOATS * sizeof(float);
  hipFuncSetAttribute(reinterpret_cast<const void*>(node_integrate),
                      hipFuncAttributeMaxDynamicSharedMemorySize,
                      (int)lds_bytes);

  hipLaunchKernelGGL(prep, dim3(64), dim3(256), 0, stream, W0, W1, W2, ws);
  hipLaunchKernelGGL(node_integrate, dim3(NB), dim3(NTH), lds_bytes, stream,
                     ts, xs, a, b0, b1, b2, b3, W3, ws, out);
}